// Round 4
// baseline (510.715 us; speedup 1.0000x reference)
//
#include <hip/hip_runtime.h>
#include <cfloat>
#include <cmath>

#define DI 128          // feature dim (= H*OUT)
#define NH 4            // heads
#define NEG_SLOPE 0.2f

// ---------------- CSR build (by dst) ----------------
__global__ void k_hist(const int* __restrict__ ei, int E, int N, int* __restrict__ counts) {
    int j = blockIdx.x * blockDim.x + threadIdx.x;
    int tot = E + N;
    if (j >= tot) return;
    int dst = (j < E) ? ei[E + j] : (j - E);   // self-loops appended
    atomicAdd(&counts[dst], 1);
}

__global__ __launch_bounds__(1024) void k_scan(const int* __restrict__ counts, int N,
                                               int* __restrict__ row_ptr, int* __restrict__ cursor) {
    __shared__ int wsum[16];
    __shared__ int carry_sh;
    int t = threadIdx.x, lane = t & 63, wv = t >> 6;
    if (t == 0) carry_sh = 0;
    __syncthreads();
    for (int base = 0; base < N; base += 1024) {
        int v = (base + t < N) ? counts[base + t] : 0;
        int incl = v;
        #pragma unroll
        for (int off = 1; off < 64; off <<= 1) {
            int y = __shfl_up(incl, off);
            if (lane >= off) incl += y;
        }
        if (lane == 63) wsum[wv] = incl;
        __syncthreads();
        if (wv == 0 && lane < 16) {
            int s = wsum[lane];
            #pragma unroll
            for (int off = 1; off < 16; off <<= 1) {
                int y = __shfl_up(s, off);
                if (lane >= off) s += y;
            }
            wsum[lane] = s;  // inclusive scan of wave sums
        }
        __syncthreads();
        int waveoff = (wv == 0) ? 0 : wsum[wv - 1];
        int carry = carry_sh;
        if (base + t < N) {
            int excl = carry + waveoff + incl - v;
            row_ptr[base + t] = excl;
            cursor[base + t]  = excl;
        }
        __syncthreads();
        if (t == 0) carry_sh = carry + wsum[15];
        __syncthreads();
    }
    if (t == 0) row_ptr[N] = carry_sh;
}

__global__ void k_scatter(const int* __restrict__ ei, int E, int N,
                          int* __restrict__ cursor, int* __restrict__ col_src) {
    int j = blockIdx.x * blockDim.x + threadIdx.x;
    int tot = E + N;
    if (j >= tot) return;
    int s, d;
    if (j < E) { s = ei[j]; d = ei[E + j]; } else { s = j - E; d = j - E; }
    int pos = atomicAdd(&cursor[d], 1);
    __builtin_nontemporal_store(s, col_src + pos);
}

// ---------------- h = x @ W  (+ fused attention halves) ----------------
// 512 threads = 8 waves. W (64KB) staged in LDS ONCE per block; block loops
// over 32-row x tiles. Wave handles 4 rows; lane owns cols (2*lane, 2*lane+1).
__global__ __launch_bounds__(512) void k_gemm(
    const float* __restrict__ x, const float* __restrict__ W,
    const float* __restrict__ a_s, const float* __restrict__ a_d,
    float* __restrict__ h, float* __restrict__ al_s, float* __restrict__ al_d,
    int N, int rows_per)
{
    __shared__ float wlds[DI * DI];   // 64 KB
    __shared__ float xs[32][DI];      // 16 KB
    int t = threadIdx.x;
    {
        const float4* Wv = reinterpret_cast<const float4*>(W);
        float4* wv = reinterpret_cast<float4*>(wlds);
        #pragma unroll
        for (int i = 0; i < 8; ++i) wv[t + i * 512] = Wv[t + i * 512];
    }
    int rbeg = blockIdx.x * rows_per;
    int rend = min(rbeg + rows_per, N);
    int lane = t & 63, wave = t >> 6;
    int c0 = lane * 2;
    int head = lane >> 4;
    float2 as2 = *reinterpret_cast<const float2*>(a_s + c0);
    float2 ad2 = *reinterpret_cast<const float2*>(a_d + c0);

    for (int base = rbeg; base < rend; base += 32) {
        __syncthreads();
        {
            int idx = t * 8;
            int r = idx >> 7, c = idx & 127;
            int row = base + r;
            float4 v0 = make_float4(0.f,0.f,0.f,0.f), v1 = v0;
            if (row < N) {
                const float4* p = reinterpret_cast<const float4*>(x + (size_t)row * DI + c);
                v0 = p[0]; v1 = p[1];
            }
            *reinterpret_cast<float4*>(&xs[r][c])     = v0;
            *reinterpret_cast<float4*>(&xs[r][c + 4]) = v1;
        }
        __syncthreads();

        int r0 = wave * 4;
        float2 acc[4];
        #pragma unroll
        for (int rr = 0; rr < 4; ++rr) acc[rr] = make_float2(0.f, 0.f);

        for (int k = 0; k < DI; k += 4) {
            float2 w0 = *reinterpret_cast<const float2*>(&wlds[(k+0)*DI + c0]);
            float2 w1 = *reinterpret_cast<const float2*>(&wlds[(k+1)*DI + c0]);
            float2 w2 = *reinterpret_cast<const float2*>(&wlds[(k+2)*DI + c0]);
            float2 w3 = *reinterpret_cast<const float2*>(&wlds[(k+3)*DI + c0]);
            #pragma unroll
            for (int rr = 0; rr < 4; ++rr) {
                float4 xv = *reinterpret_cast<const float4*>(&xs[r0 + rr][k]);
                acc[rr].x = fmaf(xv.x, w0.x, acc[rr].x);
                acc[rr].y = fmaf(xv.x, w0.y, acc[rr].y);
                acc[rr].x = fmaf(xv.y, w1.x, acc[rr].x);
                acc[rr].y = fmaf(xv.y, w1.y, acc[rr].y);
                acc[rr].x = fmaf(xv.z, w2.x, acc[rr].x);
                acc[rr].y = fmaf(xv.z, w2.y, acc[rr].y);
                acc[rr].x = fmaf(xv.w, w3.x, acc[rr].x);
                acc[rr].y = fmaf(xv.w, w3.y, acc[rr].y);
            }
        }

        #pragma unroll
        for (int rr = 0; rr < 4; ++rr) {
            int row = base + r0 + rr;
            float ps = acc[rr].x * as2.x + acc[rr].y * as2.y;
            float pd = acc[rr].x * ad2.x + acc[rr].y * ad2.y;
            #pragma unroll
            for (int msk = 1; msk <= 8; msk <<= 1) {
                ps += __shfl_xor(ps, msk);
                pd += __shfl_xor(pd, msk);
            }
            if (row < rend) {
                *reinterpret_cast<float2*>(h + (size_t)row * DI + c0) = acc[rr];
                if ((lane & 15) == 0) {
                    al_s[row * NH + head] = ps;
                    al_d[row * NH + head] = pd;
                }
            }
        }
    }
}

// ---------------- segment softmax + aggregate (one NODE per 128-thread block) ----------------
// 2 waves share the node: edge phases split across waves; gather split across
// 4 quarter-waves (32 lanes x float4 = one full 128-ch row each), stride 4.
__global__ __launch_bounds__(128) void k_agg(
    const float* __restrict__ h, const float* __restrict__ al_s, const float* __restrict__ al_d,
    const int* __restrict__ row_ptr, const int* __restrict__ col_src,
    const float* __restrict__ bias, float* __restrict__ out, int N)
{
    __shared__ float lds_p[256];    // p for 64 edge slots x 4 heads
    __shared__ float lds_e[256];    // cached logits for first 64 edges x 4 heads
    __shared__ int   lds_s[64];
    __shared__ float lds_m[2][4];
    __shared__ float lds_sm[2][4];
    __shared__ float lds_acc[128];
    int t = threadIdx.x;
    int wv = t >> 6, lane = t & 63;
    int n = blockIdx.x;

    int start = row_ptr[n], end = row_ptr[n + 1];
    int deg = end - start;               // >= 1 (self-loop)
    int h4  = lane & 3;                  // head for edge phases
    int sub = lane >> 2;                 // edge slot within wave (0..15)
    float aldn = al_d[n * NH + h4];

    // Phase A: per-head max of leaky_relu logits (both waves, 32 edges/iter);
    // cache logits of first 64 edges in LDS.
    float m = -FLT_MAX;
    for (int jb = 0; jb < deg; jb += 32) {
        int j = jb + wv * 16 + sub;
        if (j < deg) {
            int s = col_src[start + j];
            float e = al_s[s * NH + h4] + aldn;
            e = (e > 0.f) ? e : NEG_SLOPE * e;
            if (j < 64) lds_e[j * 4 + h4] = e;
            m = fmaxf(m, e);
        }
    }
    #pragma unroll
    for (int msk = 4; msk <= 32; msk <<= 1) m = fmaxf(m, __shfl_xor(m, msk));
    if (lane < 4) lds_m[wv][lane] = m;   // lane == h4 for lanes 0..3
    __syncthreads();
    m = fmaxf(lds_m[0][h4], lds_m[1][h4]);

    // Phase B/C: exp + sum + weighted gather-accumulate, 64-edge chunks
    int hw = lane >> 5;                  // half-wave (0/1)
    int cl = lane & 31;
    int c4 = cl * 4;                     // this lane's 4 channels
    int quarter = wv * 2 + hw;           // 0..3: which edge-row residue class
    int myhead = cl >> 3;                // head of this lane's channels
    float ssum = 0.f;
    float4 acc = make_float4(0.f, 0.f, 0.f, 0.f);
    for (int cb = 0; cb < deg; cb += 64) {
        int cd = min(64, deg - cb);
        __syncthreads();                 // lds_p/lds_s free from previous chunk's readers
        #pragma unroll
        for (int q = 0; q < 2; ++q) {
            int jl = wv * 32 + q * 16 + sub;
            if (jl < cd) {
                int j = cb + jl;
                int s2 = col_src[start + j];       // coalesced
                float e;
                if (j < 64) {
                    e = lds_e[j * 4 + h4];
                } else {
                    e = al_s[s2 * NH + h4] + aldn;
                    e = (e > 0.f) ? e : NEG_SLOPE * e;
                }
                float p = __expf(e - m);
                ssum += p;
                lds_p[jl * 4 + h4] = p;
                if (h4 == 0) lds_s[jl] = s2;
            }
        }
        __syncthreads();
        #pragma unroll 4
        for (int jl = quarter; jl < cd; jl += 4) {
            int s = lds_s[jl];
            float p = lds_p[jl * 4 + myhead];
            float4 hv = *reinterpret_cast<const float4*>(h + (size_t)s * DI + c4);
            acc.x = fmaf(p, hv.x, acc.x);
            acc.y = fmaf(p, hv.y, acc.y);
            acc.z = fmaf(p, hv.z, acc.z);
            acc.w = fmaf(p, hv.w, acc.w);
        }
    }
    // reduce ssum within wave (per-head), combine acc across half-waves
    #pragma unroll
    for (int msk = 4; msk <= 32; msk <<= 1) ssum += __shfl_xor(ssum, msk);
    if (lane < 4) lds_sm[wv][lane] = ssum;
    acc.x += __shfl_xor(acc.x, 32);
    acc.y += __shfl_xor(acc.y, 32);
    acc.z += __shfl_xor(acc.z, 32);
    acc.w += __shfl_xor(acc.w, 32);
    if (wv == 1 && hw == 0) *reinterpret_cast<float4*>(&lds_acc[c4]) = acc;
    __syncthreads();
    if (wv == 0 && hw == 0) {
        float4 o2 = *reinterpret_cast<const float4*>(&lds_acc[c4]);
        float sdiv = lds_sm[0][myhead] + lds_sm[1][myhead];
        float4 b4 = *reinterpret_cast<const float4*>(bias + c4);
        float4 o;
        o.x = fmaxf((acc.x + o2.x) / sdiv + b4.x, 0.f);
        o.y = fmaxf((acc.y + o2.y) / sdiv + b4.y, 0.f);
        o.z = fmaxf((acc.z + o2.z) / sdiv + b4.z, 0.f);
        o.w = fmaxf((acc.w + o2.w) / sdiv + b4.w, 0.f);
        *reinterpret_cast<float4*>(out + (size_t)n * DI + c4) = o;
    }
}

// ---------------- graph mean-pool (two-phase, parallel) ----------------
#define POOL_ROWS 64
__global__ __launch_bounds__(256) void k_pool_partial(
    const float* __restrict__ x, const int* __restrict__ batch,
    int N, float* __restrict__ gsum)
{
    int t = threadIdx.x;
    int c  = t & 127;
    int rh = t >> 7;                       // 0 or 1
    int base = blockIdx.x * POOL_ROWS;
    int lim = min(base + POOL_ROWS, N);
    int i = base + rh;
    if (i >= lim) return;
    int g_cur = batch[i];
    float acc = 0.f;
    for (; i < lim; i += 2) {
        int g = batch[i];
        if (g != g_cur) {
            atomicAdd(&gsum[(size_t)g_cur * DI + c], acc);
            acc = 0.f;
            g_cur = g;
        }
        acc += x[(size_t)i * DI + c];
    }
    atomicAdd(&gsum[(size_t)g_cur * DI + c], acc);
}

__global__ void k_pool_final(const float* __restrict__ gsum, const int* __restrict__ batch,
                             int N, float* __restrict__ gout)
{
    int g = blockIdx.x;
    int c = threadIdx.x;
    int lo = 0, hi = N;
    while (lo < hi) { int mid = (lo + hi) >> 1; if (batch[mid] < g) lo = mid + 1; else hi = mid; }
    int s0 = lo;
    lo = 0; hi = N;
    while (lo < hi) { int mid = (lo + hi) >> 1; if (batch[mid] < g + 1) lo = mid + 1; else hi = mid; }
    int s1 = lo;
    float cnt = (float)(s1 - s0);
    gout[g * DI + c] = gsum[g * DI + c] / fmaxf(cnt, 1.f);
}

extern "C" void kernel_launch(void* const* d_in, const int* in_sizes, int n_in,
                              void* d_out, int out_size, void* d_ws, size_t ws_size,
                              hipStream_t stream) {
    const float* x0    = (const float*)d_in[0];
    const int*   ei    = (const int*)  d_in[1];
    const int*   batch = (const int*)  d_in[2];
    const float* Ws    = (const float*)d_in[3];
    const float* a_src = (const float*)d_in[4];
    const float* a_dst = (const float*)d_in[5];
    const float* b     = (const float*)d_in[6];
    int N = in_sizes[2];
    int E = in_sizes[1] / 2;
    int G = (out_size - N * DI) / DI;
    float* out = (float*)d_out;

    char* ws = (char*)d_ws;
    size_t off = 0;
    auto alloc = [&](size_t bytes) {
        void* p = ws + off;
        off += (bytes + 255) & ~(size_t)255;
        return p;
    };
    float* xbuf    = (float*)alloc((size_t)N * DI * 4);
    float* hbuf    = (float*)alloc((size_t)N * DI * 4);
    float* al_s    = (float*)alloc((size_t)N * NH * 4);
    float* al_d    = (float*)alloc((size_t)N * NH * 4);
    int*   counts  = (int*)  alloc((size_t)N * 4);
    int*   row_ptr = (int*)  alloc((size_t)(N + 1) * 4);
    int*   cursor  = (int*)  alloc((size_t)N * 4);
    int*   col_src = (int*)  alloc((size_t)(E + N) * 4);
    float* gsum    = (float*)alloc((size_t)G * DI * 4);

    hipMemsetAsync(counts, 0, (size_t)N * 4, stream);
    hipMemsetAsync(gsum,   0, (size_t)G * DI * 4, stream);
    int tot = E + N;
    k_hist   <<<(tot + 255) / 256, 256, 0, stream>>>(ei, E, N, counts);
    k_scan   <<<1, 1024, 0, stream>>>(counts, N, row_ptr, cursor);
    k_scatter<<<(tot + 255) / 256, 256, 0, stream>>>(ei, E, N, cursor, col_src);

    const int GEMM_BLOCKS = 512;
    int rows_per = (N + GEMM_BLOCKS - 1) / GEMM_BLOCKS;

    const float* xin = x0;
    for (int l = 0; l < 3; ++l) {
        const float* W   = Ws    + (size_t)l * DI * DI;
        const float* as_ = a_src + (size_t)l * NH * 32;
        const float* ad_ = a_dst + (size_t)l * NH * 32;
        const float* bl  = b     + (size_t)l * DI;
        k_gemm<<<GEMM_BLOCKS, 512, 0, stream>>>(xin, W, as_, ad_, hbuf, al_s, al_d, N, rows_per);
        float* dst = (l == 2) ? out : xbuf;
        k_agg <<<N, 128, 0, stream>>>(hbuf, al_s, al_d, row_ptr, col_src, bl, dst, N);
        xin = xbuf;
    }
    k_pool_partial<<<(N + POOL_ROWS - 1) / POOL_ROWS, 256, 0, stream>>>(out, batch, N, gsum);
    k_pool_final  <<<G, DI, 0, stream>>>(gsum, batch, N, out + (size_t)N * DI);
}

// Round 5
// 381.977 us; speedup vs baseline: 1.3370x; 1.3370x over previous
//
#include <hip/hip_runtime.h>
#include <cfloat>
#include <cmath>

#define DI 128          // feature dim (= H*OUT)
#define NH 4            // heads
#define NEG_SLOPE 0.2f
#define NB 256          // blocks in binning kernels
#define BKT 64          // nodes per coarse bucket (bucket = dst >> 6)

// ================= CSR build: two-level LDS counting sort (no global atomics) =================
// Pass A: per-block LDS histogram over buckets. ht layout: [blk][B] (coalesced writes).
__global__ __launch_bounds__(256) void k_hist2(const int* __restrict__ ei, int E, int B,
                                               int epb, int* __restrict__ ht) {
    __shared__ int lh[1024];
    int t = threadIdx.x;
    for (int i = t; i < B; i += 256) lh[i] = 0;
    __syncthreads();
    int j0 = blockIdx.x * epb;
    int j1 = min(j0 + epb, E);
    for (int j = j0 + t; j < j1; j += 256) {
        int d = ei[E + j];
        atomicAdd(&lh[d >> 6], 1);
    }
    __syncthreads();
    for (int i = t; i < B; i += 256) ht[(size_t)blockIdx.x * B + i] = lh[i];
}

// Pass B1: for each bucket, exclusive-scan its NB per-block counts (in place) + total.
__global__ __launch_bounds__(256) void k_scanb(int* __restrict__ ht, int B, int* __restrict__ btot) {
    __shared__ int ws4[4];
    int b = blockIdx.x, t = threadIdx.x, lane = t & 63, wv = t >> 6;
    int v = ht[(size_t)t * B + b];
    int incl = v;
    #pragma unroll
    for (int off = 1; off < 64; off <<= 1) {
        int y = __shfl_up(incl, off);
        if (lane >= off) incl += y;
    }
    if (lane == 63) ws4[wv] = incl;
    __syncthreads();
    int carry = 0;
    #pragma unroll
    for (int w = 0; w < 4; ++w) if (w < wv) carry += ws4[w];
    ht[(size_t)t * B + b] = carry + incl - v;
    if (t == 255) btot[b] = carry + incl;
}

// Pass B2: exclusive scan of bucket totals -> bucket_base[0..B], bucket_base[B]=E.
__global__ __launch_bounds__(1024) void k_scan(const int* __restrict__ counts, int N,
                                               int* __restrict__ row_ptr, int* __restrict__ cursor) {
    __shared__ int wsum[16];
    __shared__ int carry_sh;
    int t = threadIdx.x, lane = t & 63, wv = t >> 6;
    if (t == 0) carry_sh = 0;
    __syncthreads();
    for (int base = 0; base < N; base += 1024) {
        int v = (base + t < N) ? counts[base + t] : 0;
        int incl = v;
        #pragma unroll
        for (int off = 1; off < 64; off <<= 1) {
            int y = __shfl_up(incl, off);
            if (lane >= off) incl += y;
        }
        if (lane == 63) wsum[wv] = incl;
        __syncthreads();
        if (wv == 0 && lane < 16) {
            int s = wsum[lane];
            #pragma unroll
            for (int off = 1; off < 16; off <<= 1) {
                int y = __shfl_up(s, off);
                if (lane >= off) s += y;
            }
            wsum[lane] = s;
        }
        __syncthreads();
        int waveoff = (wv == 0) ? 0 : wsum[wv - 1];
        int carry = carry_sh;
        if (base + t < N) {
            int excl = carry + waveoff + incl - v;
            row_ptr[base + t] = excl;
            cursor[base + t]  = excl;
        }
        __syncthreads();
        if (t == 0) carry_sh = carry + wsum[15];
        __syncthreads();
    }
    if (t == 0) row_ptr[N] = carry_sh;
}

// Pass C: place edges into bucket-binned array. Each (block,bucket) owns a disjoint
// consecutive output range -> L2 write-combining works (unlike global atomic scatter).
// binned word: src (16b) | dst_low6 << 16.
__global__ __launch_bounds__(256) void k_bin(const int* __restrict__ ei, int E, int B, int epb,
                                             const int* __restrict__ ht, const int* __restrict__ bucket_base,
                                             unsigned int* __restrict__ binned) {
    __shared__ int cur[1024];
    int t = threadIdx.x;
    for (int i = t; i < B; i += 256)
        cur[i] = bucket_base[i] + ht[(size_t)blockIdx.x * B + i];
    __syncthreads();
    int j0 = blockIdx.x * epb;
    int j1 = min(j0 + epb, E);
    for (int j = j0 + t; j < j1; j += 256) {
        int s = ei[j];
        int d = ei[E + j];
        int pos = atomicAdd(&cur[d >> 6], 1);       // LDS atomic
        binned[pos] = (unsigned int)s | ((unsigned int)(d & 63) << 16);
    }
}

// Pass D: one block per bucket; sort its <=~1200 edges by dst fully in LDS;
// emit row_ptr (per node) + ushort src list, coalesced.
__global__ __launch_bounds__(256) void k_sort(const unsigned int* __restrict__ binned,
                                              const int* __restrict__ bucket_base, int N, int B,
                                              unsigned short* __restrict__ col16, int* __restrict__ row_ptr) {
    __shared__ unsigned int pk[2048];
    __shared__ unsigned short ob[2048];
    __shared__ int hist[64];
    __shared__ int cur[64];
    int b = blockIdx.x, t = threadIdx.x;
    int base = bucket_base[b];
    int cnt  = bucket_base[b + 1] - base;
    if (t < 64) hist[t] = 0;
    __syncthreads();
    bool staged = (cnt <= 2048);
    for (int i = t; i < cnt; i += 256) {
        unsigned int w = binned[base + i];
        if (staged) pk[i] = w;
        atomicAdd(&hist[(w >> 16) & 63], 1);
    }
    __syncthreads();
    if (t < 64) {
        int v = hist[t];
        int incl = v;
        #pragma unroll
        for (int off = 1; off < 64; off <<= 1) {
            int y = __shfl_up(incl, off);
            if (t >= off) incl += y;
        }
        int excl = incl - v;
        cur[t] = excl;
        int n = b * BKT + t;
        if (n < N) row_ptr[n] = base + excl;
    }
    if (b == B - 1 && t == 0) row_ptr[N] = bucket_base[B];
    __syncthreads();
    if (staged) {
        for (int i = t; i < cnt; i += 256) {
            unsigned int w = pk[i];
            int pos = atomicAdd(&cur[(w >> 16) & 63], 1);
            ob[pos] = (unsigned short)(w & 0xFFFF);
        }
        __syncthreads();
        for (int i = t; i < cnt; i += 256) col16[base + i] = ob[i];
    } else {   // rare fallback: direct scattered writes
        for (int i = t; i < cnt; i += 256) {
            unsigned int w = binned[base + i];
            int pos = atomicAdd(&cur[(w >> 16) & 63], 1);
            col16[base + pos] = (unsigned short)(w & 0xFFFF);
        }
    }
}

// ---------------- h = x @ W  (+ fused attention halves) ----------------
__global__ __launch_bounds__(512) void k_gemm(
    const float* __restrict__ x, const float* __restrict__ W,
    const float* __restrict__ a_s, const float* __restrict__ a_d,
    float* __restrict__ h, float* __restrict__ al_s, float* __restrict__ al_d,
    int N, int rows_per)
{
    __shared__ float wlds[DI * DI];   // 64 KB
    __shared__ float xs[32][DI];      // 16 KB
    int t = threadIdx.x;
    {
        const float4* Wv = reinterpret_cast<const float4*>(W);
        float4* wv = reinterpret_cast<float4*>(wlds);
        #pragma unroll
        for (int i = 0; i < 8; ++i) wv[t + i * 512] = Wv[t + i * 512];
    }
    int rbeg = blockIdx.x * rows_per;
    int rend = min(rbeg + rows_per, N);
    int lane = t & 63, wave = t >> 6;
    int c0 = lane * 2;
    int head = lane >> 4;
    float2 as2 = *reinterpret_cast<const float2*>(a_s + c0);
    float2 ad2 = *reinterpret_cast<const float2*>(a_d + c0);

    for (int base = rbeg; base < rend; base += 32) {
        __syncthreads();
        {
            int idx = t * 8;
            int r = idx >> 7, c = idx & 127;
            int row = base + r;
            float4 v0 = make_float4(0.f,0.f,0.f,0.f), v1 = v0;
            if (row < N) {
                const float4* p = reinterpret_cast<const float4*>(x + (size_t)row * DI + c);
                v0 = p[0]; v1 = p[1];
            }
            *reinterpret_cast<float4*>(&xs[r][c])     = v0;
            *reinterpret_cast<float4*>(&xs[r][c + 4]) = v1;
        }
        __syncthreads();

        int r0 = wave * 4;
        float2 acc[4];
        #pragma unroll
        for (int rr = 0; rr < 4; ++rr) acc[rr] = make_float2(0.f, 0.f);

        for (int k = 0; k < DI; k += 4) {
            float2 w0 = *reinterpret_cast<const float2*>(&wlds[(k+0)*DI + c0]);
            float2 w1 = *reinterpret_cast<const float2*>(&wlds[(k+1)*DI + c0]);
            float2 w2 = *reinterpret_cast<const float2*>(&wlds[(k+2)*DI + c0]);
            float2 w3 = *reinterpret_cast<const float2*>(&wlds[(k+3)*DI + c0]);
            #pragma unroll
            for (int rr = 0; rr < 4; ++rr) {
                float4 xv = *reinterpret_cast<const float4*>(&xs[r0 + rr][k]);
                acc[rr].x = fmaf(xv.x, w0.x, acc[rr].x);
                acc[rr].y = fmaf(xv.x, w0.y, acc[rr].y);
                acc[rr].x = fmaf(xv.y, w1.x, acc[rr].x);
                acc[rr].y = fmaf(xv.y, w1.y, acc[rr].y);
                acc[rr].x = fmaf(xv.z, w2.x, acc[rr].x);
                acc[rr].y = fmaf(xv.z, w2.y, acc[rr].y);
                acc[rr].x = fmaf(xv.w, w3.x, acc[rr].x);
                acc[rr].y = fmaf(xv.w, w3.y, acc[rr].y);
            }
        }

        #pragma unroll
        for (int rr = 0; rr < 4; ++rr) {
            int row = base + r0 + rr;
            float ps = acc[rr].x * as2.x + acc[rr].y * as2.y;
            float pd = acc[rr].x * ad2.x + acc[rr].y * ad2.y;
            #pragma unroll
            for (int msk = 1; msk <= 8; msk <<= 1) {
                ps += __shfl_xor(ps, msk);
                pd += __shfl_xor(pd, msk);
            }
            if (row < rend) {
                *reinterpret_cast<float2*>(h + (size_t)row * DI + c0) = acc[rr];
                if ((lane & 15) == 0) {
                    al_s[row * NH + head] = ps;
                    al_d[row * NH + head] = pd;
                }
            }
        }
    }
}

// ---------------- segment softmax + aggregate (one wave per dst node) ----------------
// col16: edges sorted by dst (no self-loops; self-loop handled analytically).
__global__ __launch_bounds__(256) void k_agg(
    const float* __restrict__ h, const float* __restrict__ al_s, const float* __restrict__ al_d,
    const int* __restrict__ row_ptr, const unsigned short* __restrict__ col16,
    const float* __restrict__ bias, float* __restrict__ out, int N)
{
    __shared__ float lds_p[4][256];
    __shared__ float lds_e[4][256];
    __shared__ int   lds_s[4][64];
    int t = threadIdx.x;
    int wv = t >> 6, lane = t & 63;
    int n = blockIdx.x * 4 + wv;
    if (n >= N) return;

    int start = row_ptr[n], end = row_ptr[n + 1];
    int degE = end - start;              // real edges only (>=0)
    int h4  = lane & 3;
    int sub = lane >> 2;
    float aldn = al_d[n * NH + h4];
    float es = al_s[n * NH + h4] + aldn;           // self-loop logit, head h4
    es = (es > 0.f) ? es : NEG_SLOPE * es;

    // Phase A: per-head max over edges + self; cache first 64 logits in LDS
    float m = es;
    for (int jb = 0; jb < degE; jb += 16) {
        int j = jb + sub;
        if (j < degE) {
            int s = col16[start + j];
            float e = al_s[s * NH + h4] + aldn;
            e = (e > 0.f) ? e : NEG_SLOPE * e;
            if (j < 64) lds_e[wv][j * 4 + h4] = e;
            m = fmaxf(m, e);
        }
    }
    #pragma unroll
    for (int msk = 4; msk <= 32; msk <<= 1) m = fmaxf(m, __shfl_xor(m, msk));

    // Phase B/C: exp + sum + weighted gather-accumulate, 64-edge chunks
    int hw = lane >> 5;
    int cl = lane & 31;
    int c4 = cl * 4;
    int myhead = cl >> 3;
    float ssum = (sub == 0) ? __expf(es - m) : 0.f;   // self term, once per head
    float4 acc = make_float4(0.f, 0.f, 0.f, 0.f);
    for (int cb = 0; cb < degE; cb += 64) {
        int cd = min(64, degE - cb);
        #pragma unroll
        for (int q = 0; q < 4; ++q) {
            int jl = q * 16 + sub;
            if (jl < cd) {
                int j = cb + jl;
                int s = col16[start + j];
                float e;
                if (j < 64) {
                    e = lds_e[wv][j * 4 + h4];
                } else {
                    e = al_s[s * NH + h4] + aldn;
                    e = (e > 0.f) ? e : NEG_SLOPE * e;
                }
                float p = __expf(e - m);
                ssum += p;
                lds_p[wv][jl * 4 + h4] = p;
                if (h4 == 0) lds_s[wv][jl] = s;
            }
        }
        // single-wave LDS region: DS ops complete in order within a wave
        #pragma unroll 2
        for (int jl = hw; jl < cd; jl += 2) {
            int s = lds_s[wv][jl];
            float p = lds_p[wv][jl * 4 + myhead];
            float4 hv = *reinterpret_cast<const float4*>(h + (size_t)s * DI + c4);
            acc.x = fmaf(p, hv.x, acc.x);
            acc.y = fmaf(p, hv.y, acc.y);
            acc.z = fmaf(p, hv.z, acc.z);
            acc.w = fmaf(p, hv.w, acc.w);
        }
    }
    // self-loop accumulation (once: half-wave 0 only; cross-half add keeps it single)
    float m_my = __shfl(m, myhead);
    if (hw == 0) {
        float es_my = al_s[n * NH + myhead] + al_d[n * NH + myhead];
        es_my = (es_my > 0.f) ? es_my : NEG_SLOPE * es_my;
        float p_self = __expf(es_my - m_my);
        float4 hv = *reinterpret_cast<const float4*>(h + (size_t)n * DI + c4);
        acc.x = fmaf(p_self, hv.x, acc.x);
        acc.y = fmaf(p_self, hv.y, acc.y);
        acc.z = fmaf(p_self, hv.z, acc.z);
        acc.w = fmaf(p_self, hv.w, acc.w);
    }
    acc.x += __shfl_xor(acc.x, 32);
    acc.y += __shfl_xor(acc.y, 32);
    acc.z += __shfl_xor(acc.z, 32);
    acc.w += __shfl_xor(acc.w, 32);
    #pragma unroll
    for (int msk = 4; msk <= 32; msk <<= 1) ssum += __shfl_xor(ssum, msk);
    float sdiv = __shfl(ssum, myhead);

    if (hw == 0) {
        float4 b4 = *reinterpret_cast<const float4*>(bias + c4);
        float4 o;
        o.x = fmaxf(acc.x / sdiv + b4.x, 0.f);
        o.y = fmaxf(acc.y / sdiv + b4.y, 0.f);
        o.z = fmaxf(acc.z / sdiv + b4.z, 0.f);
        o.w = fmaxf(acc.w / sdiv + b4.w, 0.f);
        *reinterpret_cast<float4*>(out + (size_t)n * DI + c4) = o;
    }
}

// ---------------- graph mean-pool (two-phase, parallel) ----------------
#define POOL_ROWS 64
__global__ __launch_bounds__(256) void k_pool_partial(
    const float* __restrict__ x, const int* __restrict__ batch,
    int N, float* __restrict__ gsum)
{
    int t = threadIdx.x;
    int c  = t & 127;
    int rh = t >> 7;
    int base = blockIdx.x * POOL_ROWS;
    int lim = min(base + POOL_ROWS, N);
    int i = base + rh;
    if (i >= lim) return;
    int g_cur = batch[i];
    float acc = 0.f;
    for (; i < lim; i += 2) {
        int g = batch[i];
        if (g != g_cur) {
            atomicAdd(&gsum[(size_t)g_cur * DI + c], acc);
            acc = 0.f;
            g_cur = g;
        }
        acc += x[(size_t)i * DI + c];
    }
    atomicAdd(&gsum[(size_t)g_cur * DI + c], acc);
}

__global__ void k_pool_final(const float* __restrict__ gsum, const int* __restrict__ batch,
                             int N, float* __restrict__ gout)
{
    int g = blockIdx.x;
    int c = threadIdx.x;
    int lo = 0, hi = N;
    while (lo < hi) { int mid = (lo + hi) >> 1; if (batch[mid] < g) lo = mid + 1; else hi = mid; }
    int s0 = lo;
    lo = 0; hi = N;
    while (lo < hi) { int mid = (lo + hi) >> 1; if (batch[mid] < g + 1) lo = mid + 1; else hi = mid; }
    int s1 = lo;
    float cnt = (float)(s1 - s0);
    gout[g * DI + c] = gsum[g * DI + c] / fmaxf(cnt, 1.f);
}

extern "C" void kernel_launch(void* const* d_in, const int* in_sizes, int n_in,
                              void* d_out, int out_size, void* d_ws, size_t ws_size,
                              hipStream_t stream) {
    const float* x0    = (const float*)d_in[0];
    const int*   ei    = (const int*)  d_in[1];
    const int*   batch = (const int*)  d_in[2];
    const float* Ws    = (const float*)d_in[3];
    const float* a_src = (const float*)d_in[4];
    const float* a_dst = (const float*)d_in[5];
    const float* b     = (const float*)d_in[6];
    int N = in_sizes[2];
    int E = in_sizes[1] / 2;
    int G = (out_size - N * DI) / DI;
    float* out = (float*)d_out;

    int B = (N + BKT - 1) / BKT;        // coarse buckets (<=1024 for N<=65536)
    int epb = (E + NB - 1) / NB;

    char* ws = (char*)d_ws;
    size_t off = 0;
    auto alloc = [&](size_t bytes) {
        void* p = ws + off;
        off += (bytes + 255) & ~(size_t)255;
        return p;
    };
    float* xbuf    = (float*)alloc((size_t)N * DI * 4);
    float* hbuf    = (float*)alloc((size_t)N * DI * 4);
    float* al_s    = (float*)alloc((size_t)N * NH * 4);
    float* al_d    = (float*)alloc((size_t)N * NH * 4);
    int*   row_ptr = (int*)  alloc((size_t)(N + 1) * 4);
    unsigned short* col16 = (unsigned short*)alloc((size_t)E * 2);
    int*   btot    = (int*)  alloc((size_t)B * 4);
    int*   bbase   = (int*)  alloc((size_t)(B + 1) * 4);
    float* gsum    = (float*)alloc((size_t)G * DI * 4);
    // aliased scratch (dead before first writer of the aliasing buffer):
    int*          ht     = (int*)hbuf;            // NB*B*4 = ~0.8 MB  (dead before layer-0 k_gemm)
    unsigned int* binned = (unsigned int*)xbuf;   // E*4    = ~3.2 MB  (dead before layer-0 k_agg)

    hipMemsetAsync(gsum, 0, (size_t)G * DI * 4, stream);
    k_hist2<<<NB, 256, 0, stream>>>(ei, E, B, epb, ht);
    k_scanb<<<B, 256, 0, stream>>>(ht, B, btot);
    k_scan <<<1, 1024, 0, stream>>>(btot, B, bbase, bbase);
    k_bin  <<<NB, 256, 0, stream>>>(ei, E, B, epb, ht, bbase, binned);
    k_sort <<<B, 256, 0, stream>>>(binned, bbase, N, B, col16, row_ptr);

    const int GEMM_BLOCKS = 512;
    int rows_per = (N + GEMM_BLOCKS - 1) / GEMM_BLOCKS;

    const float* xin = x0;
    for (int l = 0; l < 3; ++l) {
        const float* W   = Ws    + (size_t)l * DI * DI;
        const float* as_ = a_src + (size_t)l * NH * 32;
        const float* ad_ = a_dst + (size_t)l * NH * 32;
        const float* bl  = b     + (size_t)l * DI;
        k_gemm<<<GEMM_BLOCKS, 512, 0, stream>>>(xin, W, as_, ad_, hbuf, al_s, al_d, N, rows_per);
        float* dst = (l == 2) ? out : xbuf;
        k_agg <<<(N + 3) / 4, 256, 0, stream>>>(hbuf, al_s, al_d, row_ptr, col16, bl, dst, N);
        xin = xbuf;
    }
    k_pool_partial<<<(N + POOL_ROWS - 1) / POOL_ROWS, 256, 0, stream>>>(out, batch, N, gsum);
    k_pool_final  <<<G, DI, 0, stream>>>(gsum, batch, N, out + (size_t)N * DI);
}

// Round 8
// 377.024 us; speedup vs baseline: 1.3546x; 1.0131x over previous
//
#include <hip/hip_runtime.h>
#include <cfloat>
#include <cmath>

#define DI 128          // feature dim (= H*OUT)
#define NH 4            // heads
#define NEG_SLOPE 0.2f
#define NB 256          // blocks in binning kernels
#define BKT 64          // nodes per coarse bucket (bucket = dst >> 6)

// ================= CSR build: two-level LDS counting sort (no global atomics) =================
__global__ __launch_bounds__(256) void k_hist2(const int* __restrict__ ei, int E, int B,
                                               int epb, int* __restrict__ ht) {
    __shared__ int lh[1024];
    int t = threadIdx.x;
    for (int i = t; i < B; i += 256) lh[i] = 0;
    __syncthreads();
    int j0 = blockIdx.x * epb;
    int j1 = min(j0 + epb, E);
    for (int j = j0 + t; j < j1; j += 256) {
        int d = ei[E + j];
        atomicAdd(&lh[d >> 6], 1);
    }
    __syncthreads();
    for (int i = t; i < B; i += 256) ht[(size_t)blockIdx.x * B + i] = lh[i];
}

__global__ __launch_bounds__(256) void k_scanb(int* __restrict__ ht, int B, int* __restrict__ btot) {
    __shared__ int ws4[4];
    int b = blockIdx.x, t = threadIdx.x, lane = t & 63, wv = t >> 6;
    int v = ht[(size_t)t * B + b];
    int incl = v;
    #pragma unroll
    for (int off = 1; off < 64; off <<= 1) {
        int y = __shfl_up(incl, off);
        if (lane >= off) incl += y;
    }
    if (lane == 63) ws4[wv] = incl;
    __syncthreads();
    int carry = 0;
    #pragma unroll
    for (int w = 0; w < 4; ++w) if (w < wv) carry += ws4[w];
    ht[(size_t)t * B + b] = carry + incl - v;
    if (t == 255) btot[b] = carry + incl;
}

__global__ __launch_bounds__(1024) void k_scan(const int* __restrict__ counts, int N,
                                               int* __restrict__ row_ptr, int* __restrict__ cursor) {
    __shared__ int wsum[16];
    __shared__ int carry_sh;
    int t = threadIdx.x, lane = t & 63, wv = t >> 6;
    if (t == 0) carry_sh = 0;
    __syncthreads();
    for (int base = 0; base < N; base += 1024) {
        int v = (base + t < N) ? counts[base + t] : 0;
        int incl = v;
        #pragma unroll
        for (int off = 1; off < 64; off <<= 1) {
            int y = __shfl_up(incl, off);
            if (lane >= off) incl += y;
        }
        if (lane == 63) wsum[wv] = incl;
        __syncthreads();
        if (wv == 0 && lane < 16) {
            int s = wsum[lane];
            #pragma unroll
            for (int off = 1; off < 16; off <<= 1) {
                int y = __shfl_up(s, off);
                if (lane >= off) s += y;
            }
            wsum[lane] = s;
        }
        __syncthreads();
        int waveoff = (wv == 0) ? 0 : wsum[wv - 1];
        int carry = carry_sh;
        if (base + t < N) {
            int excl = carry + waveoff + incl - v;
            row_ptr[base + t] = excl;
            cursor[base + t]  = excl;
        }
        __syncthreads();
        if (t == 0) carry_sh = carry + wsum[15];
        __syncthreads();
    }
    if (t == 0) row_ptr[N] = carry_sh;
}

__global__ __launch_bounds__(256) void k_bin(const int* __restrict__ ei, int E, int B, int epb,
                                             const int* __restrict__ ht, const int* __restrict__ bucket_base,
                                             unsigned int* __restrict__ binned) {
    __shared__ int cur[1024];
    int t = threadIdx.x;
    for (int i = t; i < B; i += 256)
        cur[i] = bucket_base[i] + ht[(size_t)blockIdx.x * B + i];
    __syncthreads();
    int j0 = blockIdx.x * epb;
    int j1 = min(j0 + epb, E);
    for (int j = j0 + t; j < j1; j += 256) {
        int s = ei[j];
        int d = ei[E + j];
        int pos = atomicAdd(&cur[d >> 6], 1);       // LDS atomic
        binned[pos] = (unsigned int)s | ((unsigned int)(d & 63) << 16);
    }
}

__global__ __launch_bounds__(256) void k_sort(const unsigned int* __restrict__ binned,
                                              const int* __restrict__ bucket_base, int N, int B,
                                              unsigned short* __restrict__ col16, int* __restrict__ row_ptr) {
    __shared__ unsigned int pk[2048];
    __shared__ unsigned short ob[2048];
    __shared__ int hist[64];
    __shared__ int cur[64];
    int b = blockIdx.x, t = threadIdx.x;
    int base = bucket_base[b];
    int cnt  = bucket_base[b + 1] - base;
    if (t < 64) hist[t] = 0;
    __syncthreads();
    bool staged = (cnt <= 2048);
    for (int i = t; i < cnt; i += 256) {
        unsigned int w = binned[base + i];
        if (staged) pk[i] = w;
        atomicAdd(&hist[(w >> 16) & 63], 1);
    }
    __syncthreads();
    if (t < 64) {
        int v = hist[t];
        int incl = v;
        #pragma unroll
        for (int off = 1; off < 64; off <<= 1) {
            int y = __shfl_up(incl, off);
            if (t >= off) incl += y;
        }
        int excl = incl - v;
        cur[t] = excl;
        int n = b * BKT + t;
        if (n < N) row_ptr[n] = base + excl;
    }
    if (b == B - 1 && t == 0) row_ptr[N] = bucket_base[B];
    __syncthreads();
    if (staged) {
        for (int i = t; i < cnt; i += 256) {
            unsigned int w = pk[i];
            int pos = atomicAdd(&cur[(w >> 16) & 63], 1);
            ob[pos] = (unsigned short)(w & 0xFFFF);
        }
        __syncthreads();
        for (int i = t; i < cnt; i += 256) col16[base + i] = ob[i];
    } else {
        for (int i = t; i < cnt; i += 256) {
            unsigned int w = binned[base + i];
            int pos = atomicAdd(&cur[(w >> 16) & 63], 1);
            col16[base + pos] = (unsigned short)(w & 0xFFFF);
        }
    }
}

// ---------------- h = x @ W (+ fused attention halves), fp32 ----------------
// 512 threads = 8 waves; x-tile = 64 rows. Lane: cl=lane&31 -> cols c4=cl*4;
// rh=lane>>5 -> row half. Wave w: rows w*8+rh*4 .. +3. 4 rows x 4 cols per lane,
// W read as float4 -> 2 B LDS per FMA (was 3).
__global__ __launch_bounds__(512) void k_gemm(
    const float* __restrict__ x, const float* __restrict__ W,
    const float* __restrict__ a_s, const float* __restrict__ a_d,
    float* __restrict__ h, float* __restrict__ al_s, float* __restrict__ al_d,
    int N, int rows_per)
{
    __shared__ float wlds[DI * DI];   // 64 KB
    __shared__ float xs[64][DI];      // 32 KB
    int t = threadIdx.x;
    {
        const float4* Wv = reinterpret_cast<const float4*>(W);
        float4* wv = reinterpret_cast<float4*>(wlds);
        #pragma unroll
        for (int i = 0; i < 8; ++i) wv[t + i * 512] = Wv[t + i * 512];
    }
    int rbeg = blockIdx.x * rows_per;
    int rend = min(rbeg + rows_per, N);
    int lane = t & 63, wave = t >> 6;
    int cl = lane & 31, rh = lane >> 5;
    int c4 = cl * 4;
    int head = cl >> 3;
    float4 as4 = *reinterpret_cast<const float4*>(a_s + c4);
    float4 ad4 = *reinterpret_cast<const float4*>(a_d + c4);

    for (int base = rbeg; base < rend; base += 64) {
        __syncthreads();   // xs (and wlds on iter 0) not yet in use by compute
        {
            #pragma unroll
            for (int i = 0; i < 4; ++i) {
                int idx = t + i * 512;        // float4 index; 64 rows x 32 f4 = 2048
                int r = idx >> 5;
                int c = (idx & 31) * 4;
                int row = base + r;
                float4 v = make_float4(0.f, 0.f, 0.f, 0.f);
                if (row < N) v = *reinterpret_cast<const float4*>(x + (size_t)row * DI + c);
                *reinterpret_cast<float4*>(&xs[r][c]) = v;
            }
        }
        __syncthreads();

        int r0 = wave * 8 + rh * 4;
        float4 acc[4];
        #pragma unroll
        for (int rr = 0; rr < 4; ++rr) acc[rr] = make_float4(0.f, 0.f, 0.f, 0.f);

        for (int k = 0; k < DI; k += 4) {
            float4 w0 = *reinterpret_cast<const float4*>(&wlds[(k+0)*DI + c4]);
            float4 w1 = *reinterpret_cast<const float4*>(&wlds[(k+1)*DI + c4]);
            float4 w2 = *reinterpret_cast<const float4*>(&wlds[(k+2)*DI + c4]);
            float4 w3 = *reinterpret_cast<const float4*>(&wlds[(k+3)*DI + c4]);
            #pragma unroll
            for (int rr = 0; rr < 4; ++rr) {
                float4 xv = *reinterpret_cast<const float4*>(&xs[r0 + rr][k]);
                acc[rr].x = fmaf(xv.x, w0.x, acc[rr].x);
                acc[rr].y = fmaf(xv.x, w0.y, acc[rr].y);
                acc[rr].z = fmaf(xv.x, w0.z, acc[rr].z);
                acc[rr].w = fmaf(xv.x, w0.w, acc[rr].w);
                acc[rr].x = fmaf(xv.y, w1.x, acc[rr].x);
                acc[rr].y = fmaf(xv.y, w1.y, acc[rr].y);
                acc[rr].z = fmaf(xv.y, w1.z, acc[rr].z);
                acc[rr].w = fmaf(xv.y, w1.w, acc[rr].w);
                acc[rr].x = fmaf(xv.z, w2.x, acc[rr].x);
                acc[rr].y = fmaf(xv.z, w2.y, acc[rr].y);
                acc[rr].z = fmaf(xv.z, w2.z, acc[rr].z);
                acc[rr].w = fmaf(xv.z, w2.w, acc[rr].w);
                acc[rr].x = fmaf(xv.w, w3.x, acc[rr].x);
                acc[rr].y = fmaf(xv.w, w3.y, acc[rr].y);
                acc[rr].z = fmaf(xv.w, w3.z, acc[rr].z);
                acc[rr].w = fmaf(xv.w, w3.w, acc[rr].w);
            }
        }

        #pragma unroll
        for (int rr = 0; rr < 4; ++rr) {
            int row = base + r0 + rr;
            float ps = acc[rr].x * as4.x + acc[rr].y * as4.y + acc[rr].z * as4.z + acc[rr].w * as4.w;
            float pd = acc[rr].x * ad4.x + acc[rr].y * ad4.y + acc[rr].z * ad4.z + acc[rr].w * ad4.w;
            #pragma unroll
            for (int msk = 1; msk <= 4; msk <<= 1) {   // reduce 8 lanes of same head, same rh
                ps += __shfl_xor(ps, msk);
                pd += __shfl_xor(pd, msk);
            }
            if (row < rend) {
                *reinterpret_cast<float4*>(h + (size_t)row * DI + c4) = acc[rr];
                if ((lane & 7) == 0) {
                    al_s[row * NH + head] = ps;
                    al_d[row * NH + head] = pd;
                }
            }
        }
    }
}

// ---------------- segment softmax + aggregate (one wave per dst node) ----------------
// R5-proven structure; only the gather unroll deepened 2->4.
__global__ __launch_bounds__(256) void k_agg(
    const float* __restrict__ h, const float* __restrict__ al_s, const float* __restrict__ al_d,
    const int* __restrict__ row_ptr, const unsigned short* __restrict__ col16,
    const float* __restrict__ bias, float* __restrict__ out, int N)
{
    __shared__ float lds_p[4][256];
    __shared__ float lds_e[4][256];
    __shared__ int   lds_s[4][64];
    int t = threadIdx.x;
    int wv = t >> 6, lane = t & 63;
    int n = blockIdx.x * 4 + wv;
    if (n >= N) return;

    int start = row_ptr[n], end = row_ptr[n + 1];
    int degE = end - start;              // real edges only (>=0); self-loop analytic
    int h4  = lane & 3;
    int sub = lane >> 2;
    float aldn = al_d[n * NH + h4];
    float es = al_s[n * NH + h4] + aldn;           // self-loop logit, head h4
    es = (es > 0.f) ? es : NEG_SLOPE * es;

    // Phase A: per-head max over edges + self; cache first 64 logits in LDS
    float m = es;
    for (int jb = 0; jb < degE; jb += 16) {
        int j = jb + sub;
        if (j < degE) {
            int s = col16[start + j];
            float e = al_s[s * NH + h4] + aldn;
            e = (e > 0.f) ? e : NEG_SLOPE * e;
            if (j < 64) lds_e[wv][j * 4 + h4] = e;
            m = fmaxf(m, e);
        }
    }
    #pragma unroll
    for (int msk = 4; msk <= 32; msk <<= 1) m = fmaxf(m, __shfl_xor(m, msk));

    // Phase B/C: exp + sum + weighted gather-accumulate, 64-edge chunks
    int hw = lane >> 5;
    int cl = lane & 31;
    int c4 = cl * 4;
    int myhead = cl >> 3;
    float ssum = (sub == 0) ? __expf(es - m) : 0.f;   // self term, once per head
    float4 acc = make_float4(0.f, 0.f, 0.f, 0.f);
    for (int cb = 0; cb < degE; cb += 64) {
        int cd = min(64, degE - cb);
        #pragma unroll
        for (int q = 0; q < 4; ++q) {
            int jl = q * 16 + sub;
            if (jl < cd) {
                int j = cb + jl;
                int s = col16[start + j];
                float e;
                if (j < 64) {
                    e = lds_e[wv][j * 4 + h4];
                } else {
                    e = al_s[s * NH + h4] + aldn;
                    e = (e > 0.f) ? e : NEG_SLOPE * e;
                }
                float p = __expf(e - m);
                ssum += p;
                lds_p[wv][jl * 4 + h4] = p;
                if (h4 == 0) lds_s[wv][jl] = s;
            }
        }
        // single-wave LDS region: DS ops complete in order within a wave
        #pragma unroll 4
        for (int jl = hw; jl < cd; jl += 2) {
            int s = lds_s[wv][jl];
            float p = lds_p[wv][jl * 4 + myhead];
            float4 hv = *reinterpret_cast<const float4*>(h + (size_t)s * DI + c4);
            acc.x = fmaf(p, hv.x, acc.x);
            acc.y = fmaf(p, hv.y, acc.y);
            acc.z = fmaf(p, hv.z, acc.z);
            acc.w = fmaf(p, hv.w, acc.w);
        }
    }
    // self-loop accumulation (half-wave 0 only)
    float m_my = __shfl(m, myhead);
    if (hw == 0) {
        float es_my = al_s[n * NH + myhead] + al_d[n * NH + myhead];
        es_my = (es_my > 0.f) ? es_my : NEG_SLOPE * es_my;
        float p_self = __expf(es_my - m_my);
        float4 hv = *reinterpret_cast<const float4*>(h + (size_t)n * DI + c4);
        acc.x = fmaf(p_self, hv.x, acc.x);
        acc.y = fmaf(p_self, hv.y, acc.y);
        acc.z = fmaf(p_self, hv.z, acc.z);
        acc.w = fmaf(p_self, hv.w, acc.w);
    }
    acc.x += __shfl_xor(acc.x, 32);
    acc.y += __shfl_xor(acc.y, 32);
    acc.z += __shfl_xor(acc.z, 32);
    acc.w += __shfl_xor(acc.w, 32);
    #pragma unroll
    for (int msk = 4; msk <= 32; msk <<= 1) ssum += __shfl_xor(ssum, msk);
    float sdiv = __shfl(ssum, myhead);

    if (hw == 0) {
        float4 b4 = *reinterpret_cast<const float4*>(bias + c4);
        float4 o;
        o.x = fmaxf(acc.x / sdiv + b4.x, 0.f);
        o.y = fmaxf(acc.y / sdiv + b4.y, 0.f);
        o.z = fmaxf(acc.z / sdiv + b4.z, 0.f);
        o.w = fmaxf(acc.w / sdiv + b4.w, 0.f);
        *reinterpret_cast<float4*>(out + (size_t)n * DI + c4) = o;
    }
}

// ---------------- graph mean-pool (two-phase, parallel) ----------------
#define POOL_ROWS 64
__global__ __launch_bounds__(256) void k_pool_partial(
    const float* __restrict__ x, const int* __restrict__ batch,
    int N, float* __restrict__ gsum)
{
    int t = threadIdx.x;
    int c  = t & 127;
    int rh = t >> 7;
    int base = blockIdx.x * POOL_ROWS;
    int lim = min(base + POOL_ROWS, N);
    int i = base + rh;
    if (i >= lim) return;
    int g_cur = batch[i];
    float acc = 0.f;
    for (; i < lim; i += 2) {
        int g = batch[i];
        if (g != g_cur) {
            atomicAdd(&gsum[(size_t)g_cur * DI + c], acc);
            acc = 0.f;
            g_cur = g;
        }
        acc += x[(size_t)i * DI + c];
    }
    atomicAdd(&gsum[(size_t)g_cur * DI + c], acc);
}

__global__ void k_pool_final(const float* __restrict__ gsum, const int* __restrict__ batch,
                             int N, float* __restrict__ gout)
{
    int g = blockIdx.x;
    int c = threadIdx.x;
    int lo = 0, hi = N;
    while (lo < hi) { int mid = (lo + hi) >> 1; if (batch[mid] < g) lo = mid + 1; else hi = mid; }
    int s0 = lo;
    lo = 0; hi = N;
    while (lo < hi) { int mid = (lo + hi) >> 1; if (batch[mid] < g + 1) lo = mid + 1; else hi = mid; }
    int s1 = lo;
    float cnt = (float)(s1 - s0);
    gout[g * DI + c] = gsum[g * DI + c] / fmaxf(cnt, 1.f);
}

extern "C" void kernel_launch(void* const* d_in, const int* in_sizes, int n_in,
                              void* d_out, int out_size, void* d_ws, size_t ws_size,
                              hipStream_t stream) {
    const float* x0    = (const float*)d_in[0];
    const int*   ei    = (const int*)  d_in[1];
    const int*   batch = (const int*)  d_in[2];
    const float* Ws    = (const float*)d_in[3];
    const float* a_src = (const float*)d_in[4];
    const float* a_dst = (const float*)d_in[5];
    const float* b     = (const float*)d_in[6];
    int N = in_sizes[2];
    int E = in_sizes[1] / 2;
    int G = (out_size - N * DI) / DI;
    float* out = (float*)d_out;

    int B = (N + BKT - 1) / BKT;
    int epb = (E + NB - 1) / NB;

    char* ws = (char*)d_ws;
    size_t off = 0;
    auto alloc = [&](size_t bytes) {
        void* p = ws + off;
        off += (bytes + 255) & ~(size_t)255;
        return p;
    };
    float*  xbuf    = (float*) alloc((size_t)N * DI * 4);
    float*  hbuf    = (float*) alloc((size_t)N * DI * 4);
    float*  al_s    = (float*) alloc((size_t)N * NH * 4);
    float*  al_d    = (float*) alloc((size_t)N * NH * 4);
    int*    row_ptr = (int*)   alloc((size_t)(N + 1) * 4);
    unsigned short* col16 = (unsigned short*)alloc((size_t)E * 2);
    int*    btot    = (int*)   alloc((size_t)B * 4);
    int*    bbase   = (int*)   alloc((size_t)(B + 1) * 4);
    float*  gsum    = (float*) alloc((size_t)G * DI * 4);
    // aliased scratch (dead before first writer of the aliasing buffer):
    int*          ht     = (int*)hbuf;            // NB*B*4 ~0.8 MB (dead before layer-0 k_gemm)
    unsigned int* binned = (unsigned int*)xbuf;   // E*4 ~3.2 MB    (dead before layer-0 k_agg)

    hipMemsetAsync(gsum, 0, (size_t)G * DI * 4, stream);
    k_hist2<<<NB, 256, 0, stream>>>(ei, E, B, epb, ht);
    k_scanb<<<B, 256, 0, stream>>>(ht, B, btot);
    k_scan <<<1, 1024, 0, stream>>>(btot, B, bbase, bbase);
    k_bin  <<<NB, 256, 0, stream>>>(ei, E, B, epb, ht, bbase, binned);
    k_sort <<<B, 256, 0, stream>>>(binned, bbase, N, B, col16, row_ptr);

    const int GEMM_ROWS = 64;
    int gemm_blocks = (N + GEMM_ROWS - 1) / GEMM_ROWS;

    const float* xin = x0;
    for (int l = 0; l < 3; ++l) {
        const float* W   = Ws    + (size_t)l * DI * DI;
        const float* as_ = a_src + (size_t)l * NH * 32;
        const float* ad_ = a_dst + (size_t)l * NH * 32;
        const float* bl  = b     + (size_t)l * DI;
        k_gemm<<<gemm_blocks, 512, 0, stream>>>(xin, W, as_, ad_, hbuf, al_s, al_d, N, GEMM_ROWS);
        float* dst = (l == 2) ? out : xbuf;
        k_agg <<<(N + 3) / 4, 256, 0, stream>>>(hbuf, al_s, al_d, row_ptr, col16, bl, dst, N);
        xin = xbuf;
    }
    k_pool_partial<<<(N + POOL_ROWS - 1) / POOL_ROWS, 256, 0, stream>>>(out, batch, N, gsum);
    k_pool_final  <<<G, DI, 0, stream>>>(gsum, batch, N, out + (size_t)N * DI);
}

// Round 9
// 351.391 us; speedup vs baseline: 1.4534x; 1.0729x over previous
//
#include <hip/hip_runtime.h>
#include <hip/hip_fp16.h>
#include <cfloat>
#include <cmath>

#define DI 128          // feature dim (= H*OUT)
#define NH 4            // heads
#define NEG_SLOPE 0.2f
#define NB 256          // blocks in binning kernels
#define BKT 64          // nodes per coarse bucket (bucket = dst >> 6)

// ================= CSR build: two-level LDS counting sort (no global atomics) =================
__global__ __launch_bounds__(256) void k_hist2(const int* __restrict__ ei, int E, int B,
                                               int epb, int* __restrict__ ht) {
    __shared__ int lh[1024];
    int t = threadIdx.x;
    for (int i = t; i < B; i += 256) lh[i] = 0;
    __syncthreads();
    int j0 = blockIdx.x * epb;
    int j1 = min(j0 + epb, E);
    for (int j = j0 + t; j < j1; j += 256) {
        int d = ei[E + j];
        atomicAdd(&lh[d >> 6], 1);
    }
    __syncthreads();
    for (int i = t; i < B; i += 256) ht[(size_t)blockIdx.x * B + i] = lh[i];
}

__global__ __launch_bounds__(256) void k_scanb(int* __restrict__ ht, int B, int* __restrict__ btot) {
    __shared__ int ws4[4];
    int b = blockIdx.x, t = threadIdx.x, lane = t & 63, wv = t >> 6;
    int v = ht[(size_t)t * B + b];
    int incl = v;
    #pragma unroll
    for (int off = 1; off < 64; off <<= 1) {
        int y = __shfl_up(incl, off);
        if (lane >= off) incl += y;
    }
    if (lane == 63) ws4[wv] = incl;
    __syncthreads();
    int carry = 0;
    #pragma unroll
    for (int w = 0; w < 4; ++w) if (w < wv) carry += ws4[w];
    ht[(size_t)t * B + b] = carry + incl - v;
    if (t == 255) btot[b] = carry + incl;
}

__global__ __launch_bounds__(1024) void k_scan(const int* __restrict__ counts, int N,
                                               int* __restrict__ row_ptr, int* __restrict__ cursor) {
    __shared__ int wsum[16];
    __shared__ int carry_sh;
    int t = threadIdx.x, lane = t & 63, wv = t >> 6;
    if (t == 0) carry_sh = 0;
    __syncthreads();
    for (int base = 0; base < N; base += 1024) {
        int v = (base + t < N) ? counts[base + t] : 0;
        int incl = v;
        #pragma unroll
        for (int off = 1; off < 64; off <<= 1) {
            int y = __shfl_up(incl, off);
            if (lane >= off) incl += y;
        }
        if (lane == 63) wsum[wv] = incl;
        __syncthreads();
        if (wv == 0 && lane < 16) {
            int s = wsum[lane];
            #pragma unroll
            for (int off = 1; off < 16; off <<= 1) {
                int y = __shfl_up(s, off);
                if (lane >= off) s += y;
            }
            wsum[lane] = s;
        }
        __syncthreads();
        int waveoff = (wv == 0) ? 0 : wsum[wv - 1];
        int carry = carry_sh;
        if (base + t < N) {
            int excl = carry + waveoff + incl - v;
            row_ptr[base + t] = excl;
            cursor[base + t]  = excl;
        }
        __syncthreads();
        if (t == 0) carry_sh = carry + wsum[15];
        __syncthreads();
    }
    if (t == 0) row_ptr[N] = carry_sh;
}

__global__ __launch_bounds__(256) void k_bin(const int* __restrict__ ei, int E, int B, int epb,
                                             const int* __restrict__ ht, const int* __restrict__ bucket_base,
                                             unsigned int* __restrict__ binned) {
    __shared__ int cur[1024];
    int t = threadIdx.x;
    for (int i = t; i < B; i += 256)
        cur[i] = bucket_base[i] + ht[(size_t)blockIdx.x * B + i];
    __syncthreads();
    int j0 = blockIdx.x * epb;
    int j1 = min(j0 + epb, E);
    for (int j = j0 + t; j < j1; j += 256) {
        int s = ei[j];
        int d = ei[E + j];
        int pos = atomicAdd(&cur[d >> 6], 1);       // LDS atomic
        binned[pos] = (unsigned int)s | ((unsigned int)(d & 63) << 16);
    }
}

__global__ __launch_bounds__(256) void k_sort(const unsigned int* __restrict__ binned,
                                              const int* __restrict__ bucket_base, int N, int B,
                                              unsigned short* __restrict__ col16, int* __restrict__ row_ptr) {
    __shared__ unsigned int pk[2048];
    __shared__ unsigned short ob[2048];
    __shared__ int hist[64];
    __shared__ int cur[64];
    int b = blockIdx.x, t = threadIdx.x;
    int base = bucket_base[b];
    int cnt  = bucket_base[b + 1] - base;
    if (t < 64) hist[t] = 0;
    __syncthreads();
    bool staged = (cnt <= 2048);
    for (int i = t; i < cnt; i += 256) {
        unsigned int w = binned[base + i];
        if (staged) pk[i] = w;
        atomicAdd(&hist[(w >> 16) & 63], 1);
    }
    __syncthreads();
    if (t < 64) {
        int v = hist[t];
        int incl = v;
        #pragma unroll
        for (int off = 1; off < 64; off <<= 1) {
            int y = __shfl_up(incl, off);
            if (t >= off) incl += y;
        }
        int excl = incl - v;
        cur[t] = excl;
        int n = b * BKT + t;
        if (n < N) row_ptr[n] = base + excl;
    }
    if (b == B - 1 && t == 0) row_ptr[N] = bucket_base[B];
    __syncthreads();
    if (staged) {
        for (int i = t; i < cnt; i += 256) {
            unsigned int w = pk[i];
            int pos = atomicAdd(&cur[(w >> 16) & 63], 1);
            ob[pos] = (unsigned short)(w & 0xFFFF);
        }
        __syncthreads();
        for (int i = t; i < cnt; i += 256) col16[base + i] = ob[i];
    } else {
        for (int i = t; i < cnt; i += 256) {
            unsigned int w = binned[base + i];
            int pos = atomicAdd(&cur[(w >> 16) & 63], 1);
            col16[base + pos] = (unsigned short)(w & 0xFFFF);
        }
    }
}

// ---------------- h = x @ W (+ fused attention halves); h stored fp16 ----------------
// 512 threads = 8 waves; x-tile = 64 rows; 4 rows x 4 cols per lane.
__global__ __launch_bounds__(512) void k_gemm(
    const float* __restrict__ x, const float* __restrict__ W,
    const float* __restrict__ a_s, const float* __restrict__ a_d,
    __half* __restrict__ h, float* __restrict__ al_s, float* __restrict__ al_d,
    int N, int rows_per)
{
    __shared__ float wlds[DI * DI];   // 64 KB
    __shared__ float xs[64][DI];      // 32 KB
    int t = threadIdx.x;
    {
        const float4* Wv = reinterpret_cast<const float4*>(W);
        float4* wv = reinterpret_cast<float4*>(wlds);
        #pragma unroll
        for (int i = 0; i < 8; ++i) wv[t + i * 512] = Wv[t + i * 512];
    }
    int rbeg = blockIdx.x * rows_per;
    int rend = min(rbeg + rows_per, N);
    int lane = t & 63, wave = t >> 6;
    int cl = lane & 31, rh = lane >> 5;
    int c4 = cl * 4;
    int head = cl >> 3;
    float4 as4 = *reinterpret_cast<const float4*>(a_s + c4);
    float4 ad4 = *reinterpret_cast<const float4*>(a_d + c4);

    for (int base = rbeg; base < rend; base += 64) {
        __syncthreads();
        {
            #pragma unroll
            for (int i = 0; i < 4; ++i) {
                int idx = t + i * 512;
                int r = idx >> 5;
                int c = (idx & 31) * 4;
                int row = base + r;
                float4 v = make_float4(0.f, 0.f, 0.f, 0.f);
                if (row < N) v = *reinterpret_cast<const float4*>(x + (size_t)row * DI + c);
                *reinterpret_cast<float4*>(&xs[r][c]) = v;
            }
        }
        __syncthreads();

        int r0 = wave * 8 + rh * 4;
        float4 acc[4];
        #pragma unroll
        for (int rr = 0; rr < 4; ++rr) acc[rr] = make_float4(0.f, 0.f, 0.f, 0.f);

        for (int k = 0; k < DI; k += 4) {
            float4 w0 = *reinterpret_cast<const float4*>(&wlds[(k+0)*DI + c4]);
            float4 w1 = *reinterpret_cast<const float4*>(&wlds[(k+1)*DI + c4]);
            float4 w2 = *reinterpret_cast<const float4*>(&wlds[(k+2)*DI + c4]);
            float4 w3 = *reinterpret_cast<const float4*>(&wlds[(k+3)*DI + c4]);
            #pragma unroll
            for (int rr = 0; rr < 4; ++rr) {
                float4 xv = *reinterpret_cast<const float4*>(&xs[r0 + rr][k]);
                acc[rr].x = fmaf(xv.x, w0.x, acc[rr].x);
                acc[rr].y = fmaf(xv.x, w0.y, acc[rr].y);
                acc[rr].z = fmaf(xv.x, w0.z, acc[rr].z);
                acc[rr].w = fmaf(xv.x, w0.w, acc[rr].w);
                acc[rr].x = fmaf(xv.y, w1.x, acc[rr].x);
                acc[rr].y = fmaf(xv.y, w1.y, acc[rr].y);
                acc[rr].z = fmaf(xv.y, w1.z, acc[rr].z);
                acc[rr].w = fmaf(xv.y, w1.w, acc[rr].w);
                acc[rr].x = fmaf(xv.z, w2.x, acc[rr].x);
                acc[rr].y = fmaf(xv.z, w2.y, acc[rr].y);
                acc[rr].z = fmaf(xv.z, w2.z, acc[rr].z);
                acc[rr].w = fmaf(xv.z, w2.w, acc[rr].w);
                acc[rr].x = fmaf(xv.w, w3.x, acc[rr].x);
                acc[rr].y = fmaf(xv.w, w3.y, acc[rr].y);
                acc[rr].z = fmaf(xv.w, w3.z, acc[rr].z);
                acc[rr].w = fmaf(xv.w, w3.w, acc[rr].w);
            }
        }

        #pragma unroll
        for (int rr = 0; rr < 4; ++rr) {
            int row = base + r0 + rr;
            float ps = acc[rr].x * as4.x + acc[rr].y * as4.y + acc[rr].z * as4.z + acc[rr].w * as4.w;
            float pd = acc[rr].x * ad4.x + acc[rr].y * ad4.y + acc[rr].z * ad4.z + acc[rr].w * ad4.w;
            #pragma unroll
            for (int msk = 1; msk <= 4; msk <<= 1) {   // reduce 8 lanes of same head, same rh
                ps += __shfl_xor(ps, msk);
                pd += __shfl_xor(pd, msk);
            }
            if (row < rend) {
                __half* hp = h + (size_t)row * DI + c4;
                *reinterpret_cast<__half2*>(hp)     = __floats2half2_rn(acc[rr].x, acc[rr].y);
                *reinterpret_cast<__half2*>(hp + 2) = __floats2half2_rn(acc[rr].z, acc[rr].w);
                if ((lane & 7) == 0) {
                    al_s[row * NH + head] = ps;
                    al_d[row * NH + head] = pd;
                }
            }
        }
    }
}

// ---------------- segment softmax + aggregate (one wave per dst node) ----------------
// h fp16 (halved gather payload). acc/ssum in fp64 so the fp32-rounded output is
// identical regardless of CSR edge ordering (replay determinism, see R6 post-mortem).
__global__ __launch_bounds__(256) void k_agg(
    const __half* __restrict__ h, const float* __restrict__ al_s, const float* __restrict__ al_d,
    const int* __restrict__ row_ptr, const unsigned short* __restrict__ col16,
    const float* __restrict__ bias, float* __restrict__ out, int N)
{
    __shared__ float lds_p[4][256];
    __shared__ float lds_e[4][256];
    __shared__ int   lds_s[4][64];
    int t = threadIdx.x;
    int wv = t >> 6, lane = t & 63;
    int n = blockIdx.x * 4 + wv;
    if (n >= N) return;

    int start = row_ptr[n], end = row_ptr[n + 1];
    int degE = end - start;              // real edges only (>=0); self-loop analytic
    int h4  = lane & 3;
    int sub = lane >> 2;
    float aldn = al_d[n * NH + h4];
    float es = al_s[n * NH + h4] + aldn;           // self-loop logit, head h4
    es = (es > 0.f) ? es : NEG_SLOPE * es;

    // Phase A: per-head max over edges + self; cache first 64 logits in LDS
    float m = es;
    for (int jb = 0; jb < degE; jb += 16) {
        int j = jb + sub;
        if (j < degE) {
            int s = col16[start + j];
            float e = al_s[s * NH + h4] + aldn;
            e = (e > 0.f) ? e : NEG_SLOPE * e;
            if (j < 64) lds_e[wv][j * 4 + h4] = e;
            m = fmaxf(m, e);
        }
    }
    #pragma unroll
    for (int msk = 4; msk <= 32; msk <<= 1) m = fmaxf(m, __shfl_xor(m, msk));

    // Phase B/C: exp + sum + weighted gather-accumulate, 64-edge chunks
    int hw = lane >> 5;
    int cl = lane & 31;
    int c4 = cl * 4;
    int myhead = cl >> 3;
    double ssum = (sub == 0) ? (double)__expf(es - m) : 0.0;   // self term, once per head
    double ax = 0.0, ay = 0.0, az = 0.0, aw = 0.0;
    for (int cb = 0; cb < degE; cb += 64) {
        int cd = min(64, degE - cb);
        #pragma unroll
        for (int q = 0; q < 4; ++q) {
            int jl = q * 16 + sub;
            if (jl < cd) {
                int j = cb + jl;
                int s = col16[start + j];
                float e;
                if (j < 64) {
                    e = lds_e[wv][j * 4 + h4];
                } else {
                    e = al_s[s * NH + h4] + aldn;
                    e = (e > 0.f) ? e : NEG_SLOPE * e;
                }
                float p = __expf(e - m);
                ssum += (double)p;
                lds_p[wv][jl * 4 + h4] = p;
                if (h4 == 0) lds_s[wv][jl] = s;
            }
        }
        // single-wave LDS region: DS ops complete in order within a wave
        #pragma unroll 2
        for (int jl = hw; jl < cd; jl += 2) {
            int s = lds_s[wv][jl];
            float p = lds_p[wv][jl * 4 + myhead];
            uint2 u = *reinterpret_cast<const uint2*>(h + (size_t)s * DI + c4);
            float2 f0 = __half22float2(*reinterpret_cast<__half2*>(&u.x));
            float2 f1 = __half22float2(*reinterpret_cast<__half2*>(&u.y));
            double pd = (double)p;
            ax = fma(pd, (double)f0.x, ax);
            ay = fma(pd, (double)f0.y, ay);
            az = fma(pd, (double)f1.x, az);
            aw = fma(pd, (double)f1.y, aw);
        }
    }
    // self-loop accumulation (half-wave 0 only)
    float m_my = __shfl(m, myhead);
    if (hw == 0) {
        float es_my = al_s[n * NH + myhead] + al_d[n * NH + myhead];
        es_my = (es_my > 0.f) ? es_my : NEG_SLOPE * es_my;
        double p_self = (double)__expf(es_my - m_my);
        uint2 u = *reinterpret_cast<const uint2*>(h + (size_t)n * DI + c4);
        float2 f0 = __half22float2(*reinterpret_cast<__half2*>(&u.x));
        float2 f1 = __half22float2(*reinterpret_cast<__half2*>(&u.y));
        ax = fma(p_self, (double)f0.x, ax);
        ay = fma(p_self, (double)f0.y, ay);
        az = fma(p_self, (double)f1.x, az);
        aw = fma(p_self, (double)f1.y, aw);
    }
    ax += __shfl_xor(ax, 32);
    ay += __shfl_xor(ay, 32);
    az += __shfl_xor(az, 32);
    aw += __shfl_xor(aw, 32);
    #pragma unroll
    for (int msk = 4; msk <= 32; msk <<= 1) ssum += __shfl_xor(ssum, msk);
    double sdiv = __shfl(ssum, myhead);

    if (hw == 0) {
        double inv = 1.0 / sdiv;
        float4 b4 = *reinterpret_cast<const float4*>(bias + c4);
        float4 o;
        o.x = fmaxf((float)(ax * inv) + b4.x, 0.f);
        o.y = fmaxf((float)(ay * inv) + b4.y, 0.f);
        o.z = fmaxf((float)(az * inv) + b4.z, 0.f);
        o.w = fmaxf((float)(aw * inv) + b4.w, 0.f);
        *reinterpret_cast<float4*>(out + (size_t)n * DI + c4) = o;
    }
}

// ---------------- graph mean-pool (two-phase, parallel) ----------------
#define POOL_ROWS 64
__global__ __launch_bounds__(256) void k_pool_partial(
    const float* __restrict__ x, const int* __restrict__ batch,
    int N, float* __restrict__ gsum)
{
    int t = threadIdx.x;
    int c  = t & 127;
    int rh = t >> 7;
    int base = blockIdx.x * POOL_ROWS;
    int lim = min(base + POOL_ROWS, N);
    int i = base + rh;
    if (i >= lim) return;
    int g_cur = batch[i];
    float acc = 0.f;
    for (; i < lim; i += 2) {
        int g = batch[i];
        if (g != g_cur) {
            atomicAdd(&gsum[(size_t)g_cur * DI + c], acc);
            acc = 0.f;
            g_cur = g;
        }
        acc += x[(size_t)i * DI + c];
    }
    atomicAdd(&gsum[(size_t)g_cur * DI + c], acc);
}

__global__ void k_pool_final(const float* __restrict__ gsum, const int* __restrict__ batch,
                             int N, float* __restrict__ gout)
{
    int g = blockIdx.x;
    int c = threadIdx.x;
    int lo = 0, hi = N;
    while (lo < hi) { int mid = (lo + hi) >> 1; if (batch[mid] < g) lo = mid + 1; else hi = mid; }
    int s0 = lo;
    lo = 0; hi = N;
    while (lo < hi) { int mid = (lo + hi) >> 1; if (batch[mid] < g + 1) lo = mid + 1; else hi = mid; }
    int s1 = lo;
    float cnt = (float)(s1 - s0);
    gout[g * DI + c] = gsum[g * DI + c] / fmaxf(cnt, 1.f);
}

extern "C" void kernel_launch(void* const* d_in, const int* in_sizes, int n_in,
                              void* d_out, int out_size, void* d_ws, size_t ws_size,
                              hipStream_t stream) {
    const float* x0    = (const float*)d_in[0];
    const int*   ei    = (const int*)  d_in[1];
    const int*   batch = (const int*)  d_in[2];
    const float* Ws    = (const float*)d_in[3];
    const float* a_src = (const float*)d_in[4];
    const float* a_dst = (const float*)d_in[5];
    const float* b     = (const float*)d_in[6];
    int N = in_sizes[2];
    int E = in_sizes[1] / 2;
    int G = (out_size - N * DI) / DI;
    float* out = (float*)d_out;

    int B = (N + BKT - 1) / BKT;
    int epb = (E + NB - 1) / NB;

    char* ws = (char*)d_ws;
    size_t off = 0;
    auto alloc = [&](size_t bytes) {
        void* p = ws + off;
        off += (bytes + 255) & ~(size_t)255;
        return p;
    };
    float*  xbuf    = (float*) alloc((size_t)N * DI * 4);
    __half* hbuf    = (__half*)alloc((size_t)N * DI * 2);
    float*  al_s    = (float*) alloc((size_t)N * NH * 4);
    float*  al_d    = (float*) alloc((size_t)N * NH * 4);
    int*    row_ptr = (int*)   alloc((size_t)(N + 1) * 4);
    unsigned short* col16 = (unsigned short*)alloc((size_t)E * 2);
    int*    btot    = (int*)   alloc((size_t)B * 4);
    int*    bbase   = (int*)   alloc((size_t)(B + 1) * 4);
    float*  gsum    = (float*) alloc((size_t)G * DI * 4);
    // aliased scratch (dead before first writer of the aliasing buffer):
    int*          ht     = (int*)hbuf;            // NB*B*4 ~0.8 MB (< N*DI*2; dead before layer-0 k_gemm)
    unsigned int* binned = (unsigned int*)xbuf;   // E*4 ~3.2 MB    (dead before layer-0 k_agg)

    hipMemsetAsync(gsum, 0, (size_t)G * DI * 4, stream);
    k_hist2<<<NB, 256, 0, stream>>>(ei, E, B, epb, ht);
    k_scanb<<<B, 256, 0, stream>>>(ht, B, btot);
    k_scan <<<1, 1024, 0, stream>>>(btot, B, bbase, bbase);
    k_bin  <<<NB, 256, 0, stream>>>(ei, E, B, epb, ht, bbase, binned);
    k_sort <<<B, 256, 0, stream>>>(binned, bbase, N, B, col16, row_ptr);

    const int GEMM_ROWS = 64;
    int gemm_blocks = (N + GEMM_ROWS - 1) / GEMM_ROWS;

    const float* xin = x0;
    for (int l = 0; l < 3; ++l) {
        const float* W   = Ws    + (size_t)l * DI * DI;
        const float* as_ = a_src + (size_t)l * NH * 32;
        const float* ad_ = a_dst + (size_t)l * NH * 32;
        const float* bl  = b     + (size_t)l * DI;
        k_gemm<<<gemm_blocks, 512, 0, stream>>>(xin, W, as_, ad_, hbuf, al_s, al_d, N, GEMM_ROWS);
        float* dst = (l == 2) ? out : xbuf;
        k_agg <<<(N + 3) / 4, 256, 0, stream>>>(hbuf, al_s, al_d, row_ptr, col16, bl, dst, N);
        xin = xbuf;
    }
    k_pool_partial<<<(N + POOL_ROWS - 1) / POOL_ROWS, 256, 0, stream>>>(out, batch, N, gsum);
    k_pool_final  <<<G, DI, 0, stream>>>(gsum, batch, N, out + (size_t)N * DI);
}